// Round 1
// baseline (163.441 us; speedup 1.0000x reference)
//
#include <hip/hip_runtime.h>

// 7x7 conv, stride 1, pad 3, on 64 x 512 x 512 fp32 (single channel).
// out[n,y,x] = sum_{ky,kx} x[n, y+ky-3, x+kx-3] * w[ky,kx]  (cross-correlation,
// matching lax.conv_general_dilated).

#define IMG_W 512
#define IMG_H 512
#define NIMG  64
#define TW    128          // output tile width per block
#define TH    32           // output tile height per block
#define HALO  3
#define LDS_W 136          // TW + 6 = 134, padded to multiple of 4 floats (16B)
#define LDS_H (TH + 2*HALO) // 38

__global__ __launch_bounds__(256) void conv7x7_kernel(
    const float* __restrict__ x,
    const float* __restrict__ wgt,
    float* __restrict__ out)
{
    __shared__ float tile[LDS_H * LDS_W];

    const int tid = threadIdx.x;
    const int bx  = blockIdx.x * TW;   // output x origin of tile
    const int by  = blockIdx.y * TH;   // output y origin of tile
    const int n   = blockIdx.z;

    const float* img = x + (size_t)n * (IMG_W * IMG_H);

    // ---- stage input tile (with zero-padded halo) into LDS ----
    // region: rows [by-3, by+34], cols [bx-3, bx+130]; cols 134..135 are pad.
    #pragma unroll
    for (int idx = tid; idx < LDS_H * LDS_W; idx += 256) {
        const int r  = idx / LDS_W;
        const int c  = idx - r * LDS_W;
        const int gy = by - HALO + r;
        const int gx = bx - HALO + c;
        float v = 0.0f;
        if (c < TW + 2 * HALO && (unsigned)gy < IMG_H && (unsigned)gx < IMG_W)
            v = img[gy * IMG_W + gx];
        tile[idx] = v;
    }

    // ---- weights: wave-uniform reads -> scalar regs ----
    float w[49];
    #pragma unroll
    for (int i = 0; i < 49; ++i) w[i] = wgt[i];

    __syncthreads();

    // ---- compute: 4x4 outputs per thread, row-sliding over 10 input rows ----
    const int tx = tid & 31;   // 32 threads across x
    const int ty = tid >> 5;   // 8 threads across y
    const int lx = tx * 4;     // tile col of output c=0, kx=0 read base
    const int ly = ty * 4;     // tile row base

    float acc[4][4] = {};

    #pragma unroll
    for (int r = 0; r < 10; ++r) {
        const float* rp = &tile[(ly + r) * LDS_W + lx];
        const float4 a = *(const float4*)(rp);
        const float4 b = *(const float4*)(rp + 4);
        const float4 c4 = *(const float4*)(rp + 8);
        float row[12] = { a.x, a.y, a.z, a.w,
                          b.x, b.y, b.z, b.w,
                          c4.x, c4.y, c4.z, c4.w };
        #pragma unroll
        for (int j = 0; j < 4; ++j) {
            const int ky = r - j;
            if (ky >= 0 && ky < 7) {
                #pragma unroll
                for (int kx = 0; kx < 7; ++kx) {
                    const float wv = w[ky * 7 + kx];
                    #pragma unroll
                    for (int c = 0; c < 4; ++c)
                        acc[j][c] = fmaf(row[c + kx], wv, acc[j][c]);
                }
            }
        }
    }

    // ---- store 4 rows of float4 ----
    float* o = out + (size_t)n * (IMG_W * IMG_H);
    #pragma unroll
    for (int j = 0; j < 4; ++j) {
        float4 v = make_float4(acc[j][0], acc[j][1], acc[j][2], acc[j][3]);
        *(float4*)&o[(by + ly + j) * IMG_W + bx + lx] = v;
    }
}

extern "C" void kernel_launch(void* const* d_in, const int* in_sizes, int n_in,
                              void* d_out, int out_size, void* d_ws, size_t ws_size,
                              hipStream_t stream)
{
    const float* x   = (const float*)d_in[0];
    const float* wgt = (const float*)d_in[1];
    float* out       = (float*)d_out;

    dim3 grid(IMG_W / TW, IMG_H / TH, NIMG);
    conv7x7_kernel<<<grid, 256, 0, stream>>>(x, wgt, out);
}

// Round 2
// 133.900 us; speedup vs baseline: 1.2206x; 1.2206x over previous
//
#include <hip/hip_runtime.h>

// 7x7 conv, stride 1, pad 3, on 64 x 512 x 512 fp32 (single channel).
// out[n,y,x] = sum_{ky,kx} x[n, y+ky-3, x+kx-3] * w[ky,kx]

#define IMG_W 512
#define IMG_H 512
#define NIMG  64
#define TW    256            // output tile width per block (64 lanes x float4)
#define TH    32             // output tile height per block (4 ty x 8 rows)
#define HALO  3
// LDS col c <-> global x = bx - 4 + c  (left halo padded 3->4 so global float4
// loads AND compute-side ds_read_b128 are both 16B-aligned).
// Need x up to bx+TW+2 -> c up to 262 -> round to 264 (66 float4 per row).
#define LDS_W 264
#define LDS_H (TH + 2*HALO)  // 38
#define NF4   (LDS_W / 4)    // 66

__global__ __launch_bounds__(256, 4) void conv7x7_kernel(
    const float* __restrict__ x,
    const float* __restrict__ wgt,
    float* __restrict__ out)
{
    __shared__ float tile[LDS_H * LDS_W];

    const int tid = threadIdx.x;
    const int bx  = blockIdx.x * TW;
    const int by  = blockIdx.y * TH;
    const int n   = blockIdx.z;

    const float* img = x + (size_t)n * (IMG_W * IMG_H);

    // ---- stage tile: all traffic as guarded float4 (16B-aligned) ----
    // float4 never straddles the x=0 / x=512 boundary (gx % 4 == 0), so the
    // guard is all-or-nothing per 16B chunk.
    for (int i = tid; i < LDS_H * NF4; i += 256) {
        const int r  = i / NF4;
        const int c4 = i - r * NF4;
        const int gy = by - HALO + r;
        const int gx = bx - 4 + c4 * 4;
        float4 v = make_float4(0.f, 0.f, 0.f, 0.f);
        if ((unsigned)gy < IMG_H && (unsigned)gx < IMG_W)
            v = *(const float4*)&img[gy * IMG_W + gx];
        *(float4*)&tile[r * LDS_W + c4 * 4] = v;
    }

    // ---- weights: wave-uniform -> SGPRs ----
    float w[49];
    #pragma unroll
    for (int i = 0; i < 49; ++i) w[i] = wgt[i];

    __syncthreads();

    // ---- compute: each thread does 4x x 8y outputs, sliding over 14 rows ----
    const int tx = tid & 63;   // 64 threads across x (one wave = one row strip)
    const int ty = tid >> 6;   // 4 thread-rows
    const int lx = tx * 4;     // output x within tile; LDS col base (aligned)
    const int rbase = ty * 8;  // first LDS row this thread touches

    float acc[8][4] = {};

    #pragma unroll
    for (int r = 0; r < 14; ++r) {
        const float* rp = &tile[(rbase + r) * LDS_W + lx];
        const float4 a  = *(const float4*)(rp);
        const float4 b  = *(const float4*)(rp + 4);
        const float4 c4 = *(const float4*)(rp + 8);
        // LDS col (lx + t) holds global x = bx + lx + t - 4.
        // Output (ox+c, ky, kx) needs global x = bx+lx+c+kx-3 -> t = c+kx+1.
        const float row[12] = { a.x, a.y, a.z, a.w,
                                b.x, b.y, b.z, b.w,
                                c4.x, c4.y, c4.z, c4.w };
        #pragma unroll
        for (int j = 0; j < 8; ++j) {
            const int ky = r - j;
            if (ky >= 0 && ky < 7) {
                #pragma unroll
                for (int kx = 0; kx < 7; ++kx) {
                    const float wv = w[ky * 7 + kx];
                    #pragma unroll
                    for (int c = 0; c < 4; ++c)
                        acc[j][c] = fmaf(row[c + kx + 1], wv, acc[j][c]);
                }
            }
        }
    }

    // ---- store: 8 rows of float4 per thread ----
    float* o = out + (size_t)n * (IMG_W * IMG_H);
    #pragma unroll
    for (int j = 0; j < 8; ++j) {
        float4 v = make_float4(acc[j][0], acc[j][1], acc[j][2], acc[j][3]);
        *(float4*)&o[(by + rbase + j) * IMG_W + bx + lx] = v;
    }
}

extern "C" void kernel_launch(void* const* d_in, const int* in_sizes, int n_in,
                              void* d_out, int out_size, void* d_ws, size_t ws_size,
                              hipStream_t stream)
{
    const float* x   = (const float*)d_in[0];
    const float* wgt = (const float*)d_in[1];
    float* out       = (float*)d_out;

    dim3 grid(IMG_W / TW, IMG_H / TH, NIMG);
    conv7x7_kernel<<<grid, 256, 0, stream>>>(x, wgt, out);
}